// Round 8
// baseline (454.651 us; speedup 1.0000x reference)
//
#include <hip/hip_runtime.h>
#include <math.h>

// VQ nearest-codebook, v9: 8-wave blocks -- 2x waves/SIMD on the v8 structure.
//
// v8 (303us main, 444 total): A-in-registers + B staged via global_load_lds
// into 32KB double-buffered LDS shared by 4 waves. MfmaUtil 30% (238K of 727K
// CU-cycles = counter-consistent). Remaining stall: 2 waves/SIMD cannot cover
// the per-dc full-drain barrier (m97's ~20% tax) + L2 staging latency; m114:
// wave-level overlap absorbs these when more waves are resident.
//
// v9: BM=128, 8 waves (512 thr), same 32KB staging now shared by 8 waves
// (staging L2 traffic halves, read volume unchanged), __launch_bounds__(512,2)
// -> 16 waves/CU = 4/SIMD (2x v8). Per-wave MFMA order / top-2 / butterfly /
// recheck byte-identical to v8 => absmax 0. STAGE: 512 threads cover the
// 512 hi + 512 lo 16B-granules of a chunk in one shot; linear LDS dest +
// inverse-swizzled source + swizzled read (involution; 2-way banks = free,
// v8 measured 0 conflicts).

typedef __attribute__((ext_vector_type(8))) short short8;   // 8 bf16 = 4 VGPR
typedef __attribute__((ext_vector_type(4))) float f32x4;

#define C_DIM 256
#define BM 128    // points per block (8 waves x 16 points)

__device__ __forceinline__ unsigned short f2bf(float f) {
    unsigned u = __float_as_uint(f);
    return (unsigned short)((u + 0x7fffu + ((u >> 16) & 1u)) >> 16);
}

__device__ __forceinline__ void gll16(const void* g, void* l) {
    __builtin_amdgcn_global_load_lds(
        (const __attribute__((address_space(1))) unsigned int*)g,
        (__attribute__((address_space(3))) unsigned int*)l, 16, 0, 0);
}

// cb (K x 256 fp32) -> exact e2, and (if PLANES) bf16 hi/lo planes.
template <bool PLANES>
__global__ __launch_bounds__(256) void vq_prep(
    const float* __restrict__ cb, unsigned short* __restrict__ cbh,
    unsigned short* __restrict__ cbl, float* __restrict__ e2, int K) {
    int wave = threadIdx.x >> 6;
    int lane = threadIdx.x & 63;
    int code = blockIdx.x * 4 + wave;
    if (code >= K) return;
    float4 v = ((const float4*)(cb + (size_t)code * C_DIM))[lane];
    if constexpr (PLANES) {
        unsigned short h[4], l[4];
#pragma unroll
        for (int i = 0; i < 4; ++i) {
            float f = ((const float*)&v)[i];
            unsigned short hh = f2bf(f);
            h[i] = hh;
            l[i] = f2bf(f - __uint_as_float((unsigned)hh << 16));
        }
        *(ushort4*)(cbh + (size_t)code * C_DIM + lane * 4) = make_ushort4(h[0], h[1], h[2], h[3]);
        *(ushort4*)(cbl + (size_t)code * C_DIM + lane * 4) = make_ushort4(l[0], l[1], l[2], l[3]);
    }
    float s = v.x * v.x + v.y * v.y + v.z * v.z + v.w * v.w;
#pragma unroll
    for (int off = 32; off > 0; off >>= 1) s += __shfl_down(s, off, 64);
    if (lane == 0) e2[code] = s;
}

// Stage chunk CN (64 codes x 64 dims, hi+lo) into LDS buf (CN&1).
// 512 threads: thread tid stages granule-slot s=tid (code cl=s>>3, slot
// gs=s&7); source granule g = gs ^ (cl&7). Linear dest (base + lane*16,
// wave-uniform per gll16 requirement), inverse-swizzled source.
#define STAGE(CN)                                                              \
    {                                                                          \
        const int b_ = (CN) & 1;                                               \
        const int cb0_ = ((CN) >> 2) * 64, db0_ = ((CN) & 3) * 64;             \
        const int cl_ = tid >> 3, g_ = (tid & 7) ^ (cl_ & 7);                  \
        if constexpr (PLANES) {                                                \
            const unsigned short* sh_ = cbh + (size_t)(cb0_ + cl_) * C_DIM + db0_ + g_ * 8; \
            const unsigned short* sl_ = cbl + (size_t)(cb0_ + cl_) * C_DIM + db0_ + g_ * 8; \
            gll16(sh_, smem + b_ * 16384 + w * 1024);                          \
            gll16(sl_, smem + b_ * 16384 + 8192 + w * 1024);                   \
        } else {                                                               \
            const float* sp_ = cb + (size_t)(cb0_ + cl_) * C_DIM + db0_ + g_ * 8; \
            float4 b0_ = ((const float4*)sp_)[0], b1_ = ((const float4*)sp_)[1]; \
            short8 hi_, lo_;                                                   \
            _Pragma("unroll")                                                  \
            for (int i = 0; i < 8; ++i) {                                      \
                float f_ = (i < 4) ? ((const float*)&b0_)[i]                   \
                                   : ((const float*)&b1_)[i - 4];              \
                unsigned short hh_ = f2bf(f_);                                 \
                hi_[i] = (short)hh_;                                           \
                lo_[i] = (short)f2bf(f_ - __uint_as_float((unsigned)hh_ << 16)); \
            }                                                                  \
            *(short8*)(smem + b_ * 16384 + tid * 16) = hi_;                    \
            *(short8*)(smem + b_ * 16384 + 8192 + tid * 16) = lo_;             \
        }                                                                      \
    }

// B fragments (4 code-tiles) from LDS chunk buf, k-step KSL (0/1).
#define LOADB(BH, BL, BUF, KSL)                                                \
    {                                                                          \
        _Pragma("unroll")                                                      \
        for (int nt = 0; nt < 4; ++nt) {                                       \
            int cl_ = nt * 16 + ln;                                            \
            int sl_ = ((KSL) * 4 + q) ^ (cl_ & 7);                             \
            BH[nt] = *(const short8*)(smem + (BUF) * 16384 + cl_ * 128 + sl_ * 16); \
            BL[nt] = *(const short8*)(smem + (BUF) * 16384 + 8192 + cl_ * 128 + sl_ * 16); \
        }                                                                      \
    }

// 3-pass MFMA cluster: per-acc order hh -> lh -> hl (bit-exact vs v5-v8).
#define MFMA3(AHF, ALF, BH, BL)                                                \
    {                                                                          \
        _Pragma("unroll")                                                      \
        for (int nt = 0; nt < 4; ++nt)                                         \
            acc[nt] = __builtin_amdgcn_mfma_f32_16x16x32_bf16(AHF, BH[nt], acc[nt], 0, 0, 0); \
        _Pragma("unroll")                                                      \
        for (int nt = 0; nt < 4; ++nt)                                         \
            acc[nt] = __builtin_amdgcn_mfma_f32_16x16x32_bf16(ALF, BH[nt], acc[nt], 0, 0, 0); \
        _Pragma("unroll")                                                      \
        for (int nt = 0; nt < 4; ++nt)                                         \
            acc[nt] = __builtin_amdgcn_mfma_f32_16x16x32_bf16(AHF, BL[nt], acc[nt], 0, 0, 0); \
    }

template <bool PLANES>
__global__ __launch_bounds__(512, 2) void vq_main(
    const float* __restrict__ x, const float* __restrict__ cb,
    const unsigned short* __restrict__ cbh, const unsigned short* __restrict__ cbl,
    const float* __restrict__ e2, float* __restrict__ zq, float* __restrict__ idxf,
    int K) {

    __shared__ char smem[32768];   // B double-buffer: 2 x (8KB hi + 8KB lo)

    const int tid = threadIdx.x;
    const int lane = tid & 63;
    const int w = tid >> 6;          // wave id 0..7; wave owns points w*16..+15
    const int ln = lane & 15;        // code-within-16 / A-row select
    const int q = lane >> 4;         // k-octet select
    const size_t basep = (size_t)blockIdx.x * BM;

    // ---- A fragments: direct from global x, hi/lo split, 8 k-steps ----
    short8 Ah[8], Al[8];
    {
        const float* xr = x + (basep + w * 16 + ln) * C_DIM + q * 8;
#pragma unroll
        for (int ks = 0; ks < 8; ++ks) {
            float4 a0 = ((const float4*)(xr + ks * 32))[0];
            float4 a1 = ((const float4*)(xr + ks * 32))[1];
            short8 hi, lo;
#pragma unroll
            for (int i = 0; i < 8; ++i) {
                float f = (i < 4) ? ((const float*)&a0)[i] : ((const float*)&a1)[i - 4];
                unsigned short hh = f2bf(f);
                hi[i] = (short)hh;
                lo[i] = (short)f2bf(f - __uint_as_float((unsigned)hh << 16));
            }
            Ah[ks] = hi;
            Al[ks] = lo;
        }
    }

    STAGE(0)
    __syncthreads();

    // per-lane top-2 for 4 point-slots (slot r; point = w*16 + q*4 + r)
    float d1s[4], d2s[4];
    int c1s[4], c2s[4];
#pragma unroll
    for (int r = 0; r < 4; ++r) { d1s[r] = 1e30f; d2s[r] = 1e30f; c1s[r] = 0; c2s[r] = 1; }

    const int ncg = K >> 6;   // 16 code-groups of 64
#pragma unroll 1
    for (int cg = 0; cg < ncg; ++cg) {
        f32x4 acc[4];
#pragma unroll
        for (int nt = 0; nt < 4; ++nt)
#pragma unroll
            for (int r = 0; r < 4; ++r) acc[nt][r] = 0.0f;

        int cnv[4];
        float e2v[4];
#pragma unroll
        for (int nt = 0; nt < 4; ++nt) {
            cnv[nt] = cg * 64 + nt * 16 + ln;
            e2v[nt] = e2[cnv[nt]];
        }

#pragma unroll
        for (int dc = 0; dc < 4; ++dc) {
            const int c = cg * 4 + dc;
            const int buf = dc & 1;          // == c & 1 (cg*4 even)
            if (c < 4 * (K >> 6) - 1) {
                STAGE(c + 1)
            }
            short8 Bh[4], Bl[4];
            LOADB(Bh, Bl, buf, 0)
            MFMA3(Ah[2 * dc], Al[2 * dc], Bh, Bl)
            LOADB(Bh, Bl, buf, 1)
            MFMA3(Ah[2 * dc + 1], Al[2 * dc + 1], Bh, Bl)
            __syncthreads();   // stage(c+1) landed; buf reads done before restage
        }

        // ---- per-cg top-2 update (med3 form; v7-verified) ----
#pragma unroll
        for (int nt = 0; nt < 4; ++nt)
#pragma unroll
            for (int r = 0; r < 4; ++r) {
                float d = fmaf(-2.0f, acc[nt][r], e2v[nt]);
                int cn = cnv[nt];
                bool lt1 = d < d1s[r];
                bool lt2 = d < d2s[r];
                int tc = lt1 ? c1s[r] : cn;
                c2s[r] = lt2 ? tc : c2s[r];
                c1s[r] = lt1 ? cn : c1s[r];
                d2s[r] = __builtin_amdgcn_fmed3f(d, d1s[r], d2s[r]);
                d1s[r] = fminf(d, d1s[r]);
            }
    }

    // ---- butterfly top-2 merge across the 16 ln-lanes (codes disjoint) ----
#pragma unroll
    for (int m = 1; m <= 8; m <<= 1) {
#pragma unroll
        for (int r = 0; r < 4; ++r) {
            float od1 = __shfl_xor(d1s[r], m);
            int oc1 = __shfl_xor(c1s[r], m);
            float od2 = __shfl_xor(d2s[r], m);
            int oc2 = __shfl_xor(c2s[r], m);
            bool t = (od1 < d1s[r]) || (od1 == d1s[r] && oc1 < c1s[r]);
            float hd = t ? d1s[r] : od1;   // loser of firsts
            int hc = t ? c1s[r] : oc1;
            float nd1 = t ? od1 : d1s[r];
            int nc1 = t ? oc1 : c1s[r];
            bool u = od2 < d2s[r];
            float md = u ? od2 : d2s[r];   // min of seconds
            int mc = u ? oc2 : c2s[r];
            bool v2 = (hd < md) || (hd == md && hc < mc);
            d2s[r] = v2 ? hd : md;
            c2s[r] = v2 ? hc : mc;
            d1s[r] = nd1;
            c1s[r] = nc1;
        }
    }

    // last dc-loop barrier already fenced LDS reuse
    int* sCand = (int*)smem;           // [128][2]
    int* sWin = (int*)(smem + 1024);   // [128]

    if (ln == 0) {
#pragma unroll
        for (int r = 0; r < 4; ++r) {
            int p = w * 16 + q * 4 + r;
            sCand[p * 2] = c1s[r];
            sCand[p * 2 + 1] = c2s[r];
        }
    }
    __syncthreads();

    // ---- exact fp32 recheck (v7 formula byte-for-byte): 1 thread/pair ----
    if (tid < 2 * BM) {
        int p = tid >> 1;
        int cc = sCand[tid];
        const float4* xr4 = (const float4*)(x + (basep + p) * C_DIM);
        const float4* cr4 = (const float4*)(cb + (size_t)cc * C_DIM);
        float4 s4 = {0.f, 0.f, 0.f, 0.f};
#pragma unroll 8
        for (int j = 0; j < 64; ++j) {
            float4 a = xr4[j], b = cr4[j];
            s4.x = fmaf(a.x, b.x, s4.x);
            s4.y = fmaf(a.y, b.y, s4.y);
            s4.z = fmaf(a.z, b.z, s4.z);
            s4.w = fmaf(a.w, b.w, s4.w);
        }
        float dot = (s4.x + s4.y) + (s4.z + s4.w);
        float d = fmaf(-2.0f, dot, e2[cc]);
        float od = __shfl_xor(d, 1);
        int oc = __shfl_xor(cc, 1);
        int winc = (d < od || (d == od && cc < oc)) ? cc : oc;
        if ((tid & 1) == 0) {
            sWin[p] = winc;
            idxf[basep + p] = (float)winc;
        }
    }
    __syncthreads();

    // ---- gather winning codebook rows -> zq (cb is L2-hot) ----
#pragma unroll 2
    for (int pl = 0; pl < 16; ++pl) {
        int p = w * 16 + pl;
        int cc = sWin[p];
        float4 v = ((const float4*)(cb + (size_t)cc * C_DIM))[lane];
        ((float4*)(zq + (basep + p) * C_DIM))[lane] = v;
    }
}

extern "C" void kernel_launch(void* const* d_in, const int* in_sizes, int n_in,
                              void* d_out, int out_size, void* d_ws, size_t ws_size,
                              hipStream_t stream) {
    const float* x = (const float*)d_in[0];
    const float* cb = (const float*)d_in[1];
    int N = in_sizes[0] / C_DIM;   // 131072
    int K = in_sizes[1] / C_DIM;   // 1024

    float* zq = (float*)d_out;
    float* idxf = zq + (size_t)N * C_DIM;

    // workspace: e2 (4 KiB, always) + cbh/cbl planes (1 MiB, only if it fits)
    float* e2 = (float*)d_ws;
    unsigned short* cbh = (unsigned short*)((char*)d_ws + 4096);
    unsigned short* cbl = cbh + (size_t)K * C_DIM;
    size_t need = 4096 + (size_t)K * C_DIM * 2 * sizeof(unsigned short);

    if (ws_size >= need) {
        vq_prep<true><<<dim3((K + 3) / 4), dim3(256), 0, stream>>>(cb, cbh, cbl, e2, K);
        vq_main<true><<<dim3(N / BM), dim3(512), 0, stream>>>(x, cb, cbh, cbl, e2, zq, idxf, K);
    } else {
        vq_prep<false><<<dim3((K + 3) / 4), dim3(256), 0, stream>>>(cb, cbh, cbl, e2, K);
        vq_main<false><<<dim3(N / BM), dim3(512), 0, stream>>>(x, cb, cbh, cbl, e2, zq, idxf, K);
    }
}